// Round 5
// baseline (705.016 us; speedup 1.0000x reference)
//
#include <hip/hip_runtime.h>

// Problem dims
#define BB 16
#define SS 96
#define KK 10
#define FF 256
#define IH 64
#define IW 64
#define OCH 32
#define PH 31
#define PW 31
#define NPOS 961          // 31*31
#define FDIM 30752        // 32*961
#define NIMG 1536         // 16*96

// Solver hyper-params
#define TAUI 20.0f        // 1/TAU
#define RHOC 10.0f
#define LRC  0.5f
#define NSTEPS 60

// fc_gemm split-K
#define KSPLIT 16
#define KCHE 1952

typedef _Float16 v8hf __attribute__((ext_vector_type(8)));
typedef _Float16 v4hf __attribute__((ext_vector_type(4)));
typedef float v4f __attribute__((ext_vector_type(4)));

// ---------------- K0: fc weight fp32 -> fp16 ----------------
__global__ __launch_bounds__(256)
void wcast(const float* __restrict__ w, _Float16* __restrict__ wh) {
    const size_t i = ((size_t)blockIdx.x * 256 + threadIdx.x) * 4;
    float4 v = *(const float4*)(w + i);
    v4hf o = {(_Float16)v.x, (_Float16)v.y, (_Float16)v.z, (_Float16)v.w};
    *(v4hf*)(wh + i) = o;
}

// ---------------- K1: conv3x3 valid + bias + relu + maxpool2x2 -> fp16 ----------------
__global__ __launch_bounds__(256)
void conv_pool(const float* __restrict__ X, const float* __restrict__ W,
               const float* __restrict__ bias, _Float16* __restrict__ pooled) {
    const int img = blockIdx.y;
    const int pos = blockIdx.x * 256 + threadIdx.x;
    if (pos >= NPOS) return;
    const int oy = pos / PW, ox = pos % PW;
    const int iy = 2 * oy, ix = 2 * ox;
    const float* xb = X + (size_t)img * 3 * IH * IW;
    float in[3][4][4];
#pragma unroll
    for (int c = 0; c < 3; c++)
#pragma unroll
        for (int r = 0; r < 4; r++) {
            const float* row = xb + ((size_t)c * IH + iy + r) * IW + ix;
            float2 p0 = *(const float2*)(row);
            float2 p1 = *(const float2*)(row + 2);
            in[c][r][0] = p0.x; in[c][r][1] = p0.y;
            in[c][r][2] = p1.x; in[c][r][3] = p1.y;
        }
    _Float16* outp = pooled + (size_t)img * FDIM + pos;
    for (int oc = 0; oc < OCH; oc++) {
        float a00 = 0.f, a01 = 0.f, a10 = 0.f, a11 = 0.f;
#pragma unroll
        for (int c = 0; c < 3; c++)
#pragma unroll
            for (int ky = 0; ky < 3; ky++)
#pragma unroll
                for (int kx = 0; kx < 3; kx++) {
                    const float w = W[((oc * 3 + c) * 3 + ky) * 3 + kx];
                    a00 += in[c][ky + 0][kx + 0] * w;
                    a01 += in[c][ky + 0][kx + 1] * w;
                    a10 += in[c][ky + 1][kx + 0] * w;
                    a11 += in[c][ky + 1][kx + 1] * w;
                }
        float m = fmaxf(fmaxf(a00, a01), fmaxf(a10, a11)) + bias[oc];
        outp[(size_t)oc * NPOS] = (_Float16)fmaxf(m, 0.f);
    }
}

// ---------------- K2: FC GEMM fp16 MFMA, 128x64 tile, split-K=16, plain-store partials ----------------
__global__ __launch_bounds__(256)
void fc_gemm(const _Float16* __restrict__ Ah, const _Float16* __restrict__ Wh,
             float* __restrict__ fpart) {
    __shared__ _Float16 Asl[128 * 56];
    __shared__ _Float16 Bsl[64 * 56];
    const int m0 = blockIdx.x * 128, n0 = blockIdx.y * 64;
    const int k0 = blockIdx.z * KCHE;
    const int kend = min(k0 + KCHE, FDIM);
    const int ksteps = (kend - k0) >> 5;
    const int tid = threadIdx.x;
    const int wave = tid >> 6, lane = tid & 63;
    const int quad = lane >> 4, l16 = lane & 15;
    const int wm = (wave >> 1) * 64, wn = (wave & 1) * 32;
    const int ar = tid >> 1, ac = (tid & 1) * 16;
    const int br = tid >> 2, bc = (tid & 3) * 8;
    const _Float16* Ag = Ah + (size_t)(m0 + ar) * FDIM + ac;
    const _Float16* Bg = Wh + (size_t)(n0 + br) * FDIM + bc;

    v4f acc[4][2];
#pragma unroll
    for (int i = 0; i < 4; i++)
#pragma unroll
        for (int j = 0; j < 2; j++) acc[i][j] = (v4f)(0.f);

    for (int s = 0; s < ksteps; s++) {
        const int gk = k0 + (s << 5);
        uint4 a0 = *(const uint4*)(Ag + gk);
        uint4 a1 = *(const uint4*)(Ag + gk + 8);
        uint4 b0 = *(const uint4*)(Bg + gk);
        __syncthreads();
        *(uint4*)&Asl[ar * 56 + ac] = a0;
        *(uint4*)&Asl[ar * 56 + ac + 8] = a1;
        *(uint4*)&Bsl[br * 56 + bc] = b0;
        __syncthreads();
        v8hf af[4], bf[2];
#pragma unroll
        for (int mt = 0; mt < 4; mt++)
            af[mt] = *(const v8hf*)&Asl[(wm + mt * 16 + l16) * 56 + quad * 8];
#pragma unroll
        for (int nt = 0; nt < 2; nt++)
            bf[nt] = *(const v8hf*)&Bsl[(wn + nt * 16 + l16) * 56 + quad * 8];
#pragma unroll
        for (int mt = 0; mt < 4; mt++)
#pragma unroll
            for (int nt = 0; nt < 2; nt++)
                acc[mt][nt] = __builtin_amdgcn_mfma_f32_16x16x32_f16(
                    af[mt], bf[nt], acc[mt][nt], 0, 0, 0);
    }
    float* outz = fpart + (size_t)blockIdx.z * NIMG * FF;
#pragma unroll
    for (int mt = 0; mt < 4; mt++)
#pragma unroll
        for (int nt = 0; nt < 2; nt++)
#pragma unroll
            for (int i = 0; i < 4; i++) {
                const int gm = m0 + wm + mt * 16 + quad * 4 + i;
                const int gn = n0 + wn + nt * 16 + l16;
                outz[(size_t)gm * FF + gn] = acc[mt][nt][i];
            }
}

// ---------------- K2b: sum 16 split-K partials + bias + relu ----------------
__global__ __launch_bounds__(256)
void bias_sum_relu(const float* __restrict__ fpart, const float* __restrict__ bias,
                   float* __restrict__ f) {
    const size_t idx = ((size_t)blockIdx.x * 256 + threadIdx.x) * 4;
    float4 s = make_float4(0.f, 0.f, 0.f, 0.f);
#pragma unroll
    for (int z = 0; z < KSPLIT; z++) {
        float4 v = *(const float4*)(fpart + (size_t)z * NIMG * FF + idx);
        s.x += v.x; s.y += v.y; s.z += v.z; s.w += v.w;
    }
    const int col = (int)(idx & (FF - 1));
    float4 bv = *(const float4*)(bias + col);
    float4 o;
    o.x = fmaxf(s.x + bv.x, 0.f);
    o.y = fmaxf(s.y + bv.y, 0.f);
    o.z = fmaxf(s.z + bv.z, 0.f);
    o.w = fmaxf(s.w + bv.w, 0.f);
    *(float4*)(f + idx) = o;
}

// ---------------- K3a: row squared norms ----------------
__global__ __launch_bounds__(512)
void rownorm(const float* __restrict__ feats, float* __restrict__ n2) {
    const int b = blockIdx.x;
    const int tid = threadIdx.x, hw = tid >> 5, l = tid & 31;
#pragma unroll
    for (int r = 0; r < 6; r++) {
        const int row = hw * 6 + r;
        const float* fr = feats + ((size_t)b * SS + row) * FF;
        float s = 0.f;
#pragma unroll
        for (int u = 0; u < 8; u++) { float v = fr[l + 32 * u]; s += v * v; }
#pragma unroll
        for (int mm = 16; mm >= 1; mm >>= 1) s += __shfl_xor(s, mm);
        if (l == 0) n2[b * SS + row] = s;
    }
}

// ---------------- K3b: D = clamp(n2_i + n2_j - 2<f_i,f_j>, 0) ----------------
__global__ __launch_bounds__(256)
void dmat(const float* __restrict__ feats, const float* __restrict__ n2,
          float* __restrict__ Dm) {
    const int i0 = blockIdx.x * 16, j0 = blockIdx.y * 16, b = blockIdx.z;
    __shared__ float fi[16][260], fj[16][260];
    const int tid = threadIdx.x;
    const int r = tid >> 4, c0 = (tid & 15) * 16;
    const float* fbase = feats + (size_t)b * SS * FF;
#pragma unroll
    for (int v = 0; v < 16; v += 4) {
        float4 a = *(const float4*)(fbase + (size_t)(i0 + r) * FF + c0 + v);
        float4 w = *(const float4*)(fbase + (size_t)(j0 + r) * FF + c0 + v);
        *(float4*)&fi[r][c0 + v] = a;
        *(float4*)&fj[r][c0 + v] = w;
    }
    __syncthreads();
    const int ti = tid >> 4, tj = tid & 15;
    float dot = 0.f;
#pragma unroll 4
    for (int f = 0; f < FF; f += 4) {
        float4 a = *(const float4*)&fi[ti][f];
        float4 w = *(const float4*)&fj[tj][f];
        dot += a.x * w.x + a.y * w.y + a.z * w.z + a.w * w.w;
    }
    const int i = i0 + ti, j = j0 + tj;
    const float d = n2[b * SS + i] + n2[b * SS + j] - 2.f * dot;
    Dm[((size_t)b * SS + i) * SS + j] = fmaxf(d, 0.f);
}

// ---------------- K4: robust-OT solve, v4 ----------------
// Flag-line barrier: per b one 64B line of 10 step-number flags; wave0 lanes
// 0-9 poll with a single coalesced device-scope load + ballot. The lambda
// part of the A-update (local: needs only own cost and SD=cd*rz) executes
// BEFORE the poll, overlapping the peers' publish latency; the M part
// applies after p arrives. Exact decomposition of the original update.
__global__ __launch_bounds__(512)
void ot_kernel(const float* __restrict__ Dg, const float* __restrict__ Qg,
               const float* __restrict__ thetag, float* __restrict__ ppub,
               unsigned* __restrict__ bar, float* __restrict__ out) {
    const int bk = blockIdx.x;
    const int b = bk / KK, k = bk % KK;
    const int tid = threadIdx.x;
    const int hw = tid >> 5, l = tid & 31;

    __shared__ float ppart[16][SS];
    __shared__ float cpart[16];
    __shared__ float Msh[SS];
    __shared__ float pown[SS];

    float a[6][3], e[6][3], dre[6][3], rz[6], qi[6], cdrz[6];

    const float* Db = Dg + (size_t)b * SS * SS;
    const float* Qb = Qg + ((size_t)b * KK + k) * SS;
#pragma unroll
    for (int r = 0; r < 6; r++) {
        const int i = hw * 6 + r;
#pragma unroll
        for (int u = 0; u < 3; u++) dre[r][u] = Db[i * SS + l + 32 * u];
        qi[r] = Qb[i];
    }
    const float th = thetag[k];
    unsigned* flags = bar + b * 16;   // one 64B line per b
    float cost;

    // collect: ppart -> pown (LDS), cost (all threads), publish p + flag
    auto collect_publish = [&](int buf, unsigned flagval, bool publish) {
        __syncthreads();
        float c = 0.f;
#pragma unroll
        for (int h = 0; h < 16; h++) c += cpart[h];
        cost = c;
        if (tid < SS) {
            float s = 0.f;
#pragma unroll
            for (int h = 0; h < 16; h++) s += ppart[h][tid];
            pown[tid] = s;
            if (publish)
                __hip_atomic_store(&ppub[(((size_t)buf * BB + b) * KK + k) * SS + tid],
                                   s, __ATOMIC_RELAXED, __HIP_MEMORY_SCOPE_AGENT);
        }
        if (publish) {
            asm volatile("s_waitcnt vmcnt(0)" ::: "memory");
            __syncthreads();
            if (tid == 0)
                __hip_atomic_store(&flags[k], flagval, __ATOMIC_RELAXED,
                                   __HIP_MEMORY_SCOPE_AGENT);
        }
    };

    // ---- init pass: A=0 -> e=1, z=96 ----
    {
        float cd[6];
#pragma unroll
        for (int r = 0; r < 6; r++) {
#pragma unroll
            for (int u = 0; u < 3; u++) { a[r][u] = 0.f; e[r][u] = 1.f; }
            rz[r] = 1.f / 96.f;
            cd[r] = dre[r][0] + dre[r][1] + dre[r][2];
        }
#pragma unroll
        for (int mm = 16; mm >= 1; mm >>= 1)
#pragma unroll
            for (int r = 0; r < 6; r++) cd[r] += __shfl_xor(cd[r], mm);
        float pp0 = 0.f, cc = 0.f;
#pragma unroll
        for (int r = 0; r < 6; r++) {
            const float scale = qi[r] * rz[r];
            pp0 += scale;
            cc += scale * cd[r];
            cdrz[r] = cd[r] * rz[r];
        }
        ppart[hw][l] = pp0; ppart[hw][l + 32] = pp0; ppart[hw][l + 64] = pp0;
        if (l == 0) cpart[hw] = cc;
        collect_publish(0, 1u, true);
    }

    for (int t = 0; t < NSTEPS; t++) {
        // ---- local lambda-part of the update (overlaps peers' publish) ----
        const float lam = 2.f * RHOC * fmaxf(cost - th, 0.f);
#pragma unroll
        for (int r = 0; r < 6; r++) {
            const float sca = LRC * qi[r] * rz[r] * lam;
            a[r][0] -= sca * e[r][0] * (dre[r][0] - cdrz[r]);
            a[r][1] -= sca * e[r][1] * (dre[r][1] - cdrz[r]);
            a[r][2] -= sca * e[r][2] * (dre[r][2] - cdrz[r]);
        }
        // ---- wait for all 10 flags >= t+1 (wave0 polls one line) ----
        if (tid < 64) {
            const unsigned want = (unsigned)(t + 1);
            for (;;) {
                unsigned fv = (tid < KK)
                    ? __hip_atomic_load(&flags[tid], __ATOMIC_RELAXED,
                                        __HIP_MEMORY_SCOPE_AGENT)
                    : want;
                if (__ballot(fv >= want) == ~0ull) break;
                __builtin_amdgcn_s_sleep(1);
            }
        }
        __syncthreads();
        // ---- M phase ----
        const int rbuf = t & 1;
        if (tid < SS) {
            const float* ps = ppub + (((size_t)rbuf * BB + b) * KK) * SS + tid;
            float v[KK];
            float mx = -1e30f;
#pragma unroll
            for (int kk2 = 0; kk2 < KK; kk2++) {
                v[kk2] = __hip_atomic_load(&ps[kk2 * SS], __ATOMIC_RELAXED,
                                           __HIP_MEMORY_SCOPE_AGENT) * TAUI;
                mx = fmaxf(mx, v[kk2]);
            }
            float sum = 0.f;
#pragma unroll
            for (int kk2 = 0; kk2 < KK; kk2++) sum += __expf(v[kk2] - mx);
            Msh[tid] = __expf(v[k] - mx) * __builtin_amdgcn_rcpf(sum);
        }
        __syncthreads();
        const float M0 = Msh[l], M1 = Msh[l + 32], M2 = Msh[l + 64];

        // SM = <s, M> per row, batch-reduced
        float sm[6];
#pragma unroll
        for (int r = 0; r < 6; r++)
            sm[r] = (e[r][0] * M0 + e[r][1] * M1 + e[r][2] * M2) * rz[r];
#pragma unroll
        for (int mm = 16; mm >= 1; mm >>= 1)
#pragma unroll
            for (int r = 0; r < 6; r++) sm[r] += __shfl_xor(sm[r], mm);

        // M-part update + row maxima
        float mrow[6];
#pragma unroll
        for (int r = 0; r < 6; r++) {
            const float cq = LRC * qi[r] * rz[r];
            a[r][0] -= cq * e[r][0] * (M0 - sm[r]);
            a[r][1] -= cq * e[r][1] * (M1 - sm[r]);
            a[r][2] -= cq * e[r][2] * (M2 - sm[r]);
            mrow[r] = fmaxf(a[r][0], fmaxf(a[r][1], a[r][2]));
        }
#pragma unroll
        for (int mm = 16; mm >= 1; mm >>= 1)
#pragma unroll
            for (int r = 0; r < 6; r++) mrow[r] = fmaxf(mrow[r], __shfl_xor(mrow[r], mm));

        // exp, z & cost partials
        float zz[6], cd[6];
#pragma unroll
        for (int r = 0; r < 6; r++) {
            e[r][0] = __expf(a[r][0] - mrow[r]);
            e[r][1] = __expf(a[r][1] - mrow[r]);
            e[r][2] = __expf(a[r][2] - mrow[r]);
            zz[r] = e[r][0] + e[r][1] + e[r][2];
            cd[r] = e[r][0] * dre[r][0] + e[r][1] * dre[r][1] + e[r][2] * dre[r][2];
        }
#pragma unroll
        for (int mm = 16; mm >= 1; mm >>= 1)
#pragma unroll
            for (int r = 0; r < 6; r++) {
                zz[r] += __shfl_xor(zz[r], mm);
                cd[r] += __shfl_xor(cd[r], mm);
            }

        // p-partials + cost partials
        float pp0 = 0.f, pp1 = 0.f, pp2 = 0.f, cc = 0.f;
#pragma unroll
        for (int r = 0; r < 6; r++) {
            const float rzz = __builtin_amdgcn_rcpf(zz[r]);
            rz[r] = rzz;
            cdrz[r] = cd[r] * rzz;
            const float scale = qi[r] * rzz;
            pp0 += scale * e[r][0];
            pp1 += scale * e[r][1];
            pp2 += scale * e[r][2];
            cc += scale * cd[r];
        }
        ppart[hw][l] = pp0; ppart[hw][l + 32] = pp1; ppart[hw][l + 64] = pp2;
        if (l == 0) cpart[hw] = cc;
        collect_publish((t + 1) & 1, (unsigned)(t + 2), t < NSTEPS - 1);
    }
    __syncthreads();
    if (tid < SS) out[((size_t)b * KK + k) * SS + tid] = pown[tid];
}

// ---------------- launch ----------------
extern "C" void kernel_launch(void* const* d_in, const int* in_sizes, int n_in,
                              void* d_out, int out_size, void* d_ws, size_t ws_size,
                              hipStream_t stream) {
    const float* X     = (const float*)d_in[0];
    const float* Q     = (const float*)d_in[1];
    const float* convw = (const float*)d_in[2];
    const float* convb = (const float*)d_in[3];
    const float* fcw   = (const float*)d_in[4];
    const float* fcb   = (const float*)d_in[5];
    const float* theta = (const float*)d_in[6];
    float* out = (float*)d_out;

    char* ws = (char*)d_ws;
    size_t off = 0;
    auto take = [&](size_t nbytes) {
        char* p = ws + off;
        off += (nbytes + 255) & ~(size_t)255;
        return (void*)p;
    };
    _Float16* pooled = (_Float16*)take((size_t)NIMG * FDIM * 2);       // 94.5 MB
    _Float16* Wh     = (_Float16*)take((size_t)FF * FDIM * 2);         // 15.7 MB
    float*    fpart  = (float*)take((size_t)KSPLIT * NIMG * FF * 4);   // 25.2 MB
    float*    feats  = (float*)take((size_t)NIMG * FF * 4);
    float*    n2     = (float*)take((size_t)NIMG * 4);
    float*    Dm     = (float*)take((size_t)BB * SS * SS * 4);
    float*    ppub   = (float*)take((size_t)2 * BB * KK * SS * 4);
    unsigned* bar    = (unsigned*)take((size_t)BB * 16 * 4);

    hipMemsetAsync(bar, 0, (size_t)BB * 16 * 4, stream);  // flag lines

    hipLaunchKernelGGL(wcast, dim3((FF * FDIM) / 1024), dim3(256), 0, stream, fcw, Wh);
    hipLaunchKernelGGL(conv_pool, dim3(4, NIMG), dim3(256), 0, stream, X, convw, convb, pooled);
    hipLaunchKernelGGL(fc_gemm, dim3(12, 4, KSPLIT), dim3(256), 0, stream, pooled, Wh, fpart);
    hipLaunchKernelGGL(bias_sum_relu, dim3(NIMG * FF / 1024), dim3(256), 0, stream, fpart, fcb, feats);
    hipLaunchKernelGGL(rownorm, dim3(BB), dim3(512), 0, stream, feats, n2);
    hipLaunchKernelGGL(dmat, dim3(6, 6, BB), dim3(256), 0, stream, feats, n2, Dm);
    hipLaunchKernelGGL(ot_kernel, dim3(BB * KK), dim3(512), 0, stream, Dm, Q, theta, ppub, bar, out);
}

// Round 7
// 610.035 us; speedup vs baseline: 1.1557x; 1.1557x over previous
//
#include <hip/hip_runtime.h>

// Problem dims
#define BB 16
#define SS 96
#define KK 10
#define FF 256
#define IH 64
#define IW 64
#define OCH 32
#define PH 31
#define PW 31
#define NPOS 961          // 31*31
#define FDIM 30752        // 32*961
#define NIMG 1536         // 16*96

// Solver hyper-params
#define TAUI 20.0f        // 1/TAU
#define RHOC 10.0f
#define LRC  0.5f
#define NSTEPS 60

// fc_gemm split-K
#define KSPLIT 16
#define KCHE 1952

typedef _Float16 v8hf __attribute__((ext_vector_type(8)));
typedef _Float16 v4hf __attribute__((ext_vector_type(4)));
typedef __fp16 h2 __attribute__((ext_vector_type(2)));   // fdot2 / cvt_pkrtz operand type
typedef float v4f __attribute__((ext_vector_type(4)));

// ---------------- K0a: fc weight fp32 -> fp16 ----------------
__global__ __launch_bounds__(256)
void wcast(const float* __restrict__ w, _Float16* __restrict__ wh) {
    const size_t i = ((size_t)blockIdx.x * 256 + threadIdx.x) * 4;
    float4 v = *(const float4*)(w + i);
    v4hf o = {(_Float16)v.x, (_Float16)v.y, (_Float16)v.z, (_Float16)v.w};
    *(v4hf*)(wh + i) = o;
}

// ---------------- K0b: conv weight -> paired fp16 quads ----------------
// per (oc,c,ky): 8 halves = (w0,w1),(w2,0),(0,w0),(w1,w2)
__global__ __launch_bounds__(64)
void wprep(const float* __restrict__ w, __fp16* __restrict__ wp) {
    const int t = blockIdx.x * 64 + threadIdx.x;   // 288 triples
    if (t >= 288) return;
    const float* s = w + t * 3;
    const __fp16 w0 = (__fp16)s[0], w1 = (__fp16)s[1], w2 = (__fp16)s[2];
    __fp16* d = wp + t * 8;
    d[0] = w0; d[1] = w1;
    d[2] = w2; d[3] = (__fp16)0.f;
    d[4] = (__fp16)0.f; d[5] = w0;
    d[6] = w1; d[7] = w2;
}

// ---------------- K1: conv3x3 + bias + relu + maxpool2x2 -> fp16, via v_dot2_f32_f16 ----------------
// W staged once in LDS (broadcast b128 reads); input window as half2 pairs.
__global__ __launch_bounds__(256)
void conv_pool(const float* __restrict__ X, const uint4* __restrict__ wp,
               const float* __restrict__ bias, _Float16* __restrict__ pooled) {
    __shared__ uint4 wsl[288];
    const int tid = threadIdx.x;
    for (int i = tid; i < 288; i += 256) wsl[i] = wp[i];
    __syncthreads();

    const int img = blockIdx.y;
    const int pos = blockIdx.x * 256 + tid;
    if (pos >= NPOS) return;
    const int oy = pos / PW, ox = pos % PW;
    const int iy = 2 * oy, ix = 2 * ox;
    const float* xb = X + (size_t)img * 3 * IH * IW;
    h2 inh[3][4][2];
#pragma unroll
    for (int c = 0; c < 3; c++)
#pragma unroll
        for (int r = 0; r < 4; r++) {
            const float* row = xb + ((size_t)c * IH + iy + r) * IW + ix;
            float2 p0 = *(const float2*)(row);
            float2 p1 = *(const float2*)(row + 2);
            inh[c][r][0] = __builtin_amdgcn_cvt_pkrtz(p0.x, p0.y);
            inh[c][r][1] = __builtin_amdgcn_cvt_pkrtz(p1.x, p1.y);
        }
    _Float16* outp = pooled + (size_t)img * FDIM + pos;
    for (int oc = 0; oc < OCH; oc++) {
        float a00 = 0.f, a01 = 0.f, a10 = 0.f, a11 = 0.f;
#pragma unroll
        for (int c = 0; c < 3; c++)
#pragma unroll
            for (int ky = 0; ky < 3; ky++) {
                const h2* q = (const h2*)(wsl + oc * 9 + c * 3 + ky);
                a00 = __builtin_amdgcn_fdot2(inh[c][ky][0], q[0], a00, false);
                a00 = __builtin_amdgcn_fdot2(inh[c][ky][1], q[1], a00, false);
                a01 = __builtin_amdgcn_fdot2(inh[c][ky][0], q[2], a01, false);
                a01 = __builtin_amdgcn_fdot2(inh[c][ky][1], q[3], a01, false);
                a10 = __builtin_amdgcn_fdot2(inh[c][ky + 1][0], q[0], a10, false);
                a10 = __builtin_amdgcn_fdot2(inh[c][ky + 1][1], q[1], a10, false);
                a11 = __builtin_amdgcn_fdot2(inh[c][ky + 1][0], q[2], a11, false);
                a11 = __builtin_amdgcn_fdot2(inh[c][ky + 1][1], q[3], a11, false);
            }
        float m = fmaxf(fmaxf(a00, a01), fmaxf(a10, a11)) + bias[oc];
        outp[(size_t)oc * NPOS] = (_Float16)fmaxf(m, 0.f);
    }
}

// ---------------- K2: FC GEMM fp16 MFMA, 64x128 tile, split-K=16, plain-store partials ----------------
// n-wide tile halves A (pooled) HBM re-fetch: read x2 instead of x4.
__global__ __launch_bounds__(256)
void fc_gemm(const _Float16* __restrict__ Ah, const _Float16* __restrict__ Wh,
             float* __restrict__ fpart) {
    __shared__ _Float16 Asl[64 * 56];
    __shared__ _Float16 Bsl[128 * 56];
    const int m0 = blockIdx.x * 64, n0 = blockIdx.y * 128;
    const int k0 = blockIdx.z * KCHE;
    const int kend = min(k0 + KCHE, FDIM);
    const int ksteps = (kend - k0) >> 5;
    const int tid = threadIdx.x;
    const int wave = tid >> 6, lane = tid & 63;
    const int quad = lane >> 4, l16 = lane & 15;
    const int wm = (wave & 1) * 32, wn = (wave >> 1) * 64;
    const int ar = tid >> 2, ac = (tid & 3) * 8;     // 64 rows x 1 uint4
    const int br = tid >> 1, bc = (tid & 1) * 16;    // 128 rows x 2 uint4
    const _Float16* Ag = Ah + (size_t)(m0 + ar) * FDIM + ac;
    const _Float16* Bg = Wh + (size_t)(n0 + br) * FDIM + bc;

    v4f acc[2][4];
#pragma unroll
    for (int i = 0; i < 2; i++)
#pragma unroll
        for (int j = 0; j < 4; j++) acc[i][j] = (v4f)(0.f);

    for (int s = 0; s < ksteps; s++) {
        const int gk = k0 + (s << 5);
        uint4 a0 = *(const uint4*)(Ag + gk);
        uint4 b0 = *(const uint4*)(Bg + gk);
        uint4 b1 = *(const uint4*)(Bg + gk + 8);
        __syncthreads();
        *(uint4*)&Asl[ar * 56 + ac] = a0;
        *(uint4*)&Bsl[br * 56 + bc] = b0;
        *(uint4*)&Bsl[br * 56 + bc + 8] = b1;
        __syncthreads();
        v8hf af[2], bf[4];
#pragma unroll
        for (int mt = 0; mt < 2; mt++)
            af[mt] = *(const v8hf*)&Asl[(wm + mt * 16 + l16) * 56 + quad * 8];
#pragma unroll
        for (int nt = 0; nt < 4; nt++)
            bf[nt] = *(const v8hf*)&Bsl[(wn + nt * 16 + l16) * 56 + quad * 8];
#pragma unroll
        for (int mt = 0; mt < 2; mt++)
#pragma unroll
            for (int nt = 0; nt < 4; nt++)
                acc[mt][nt] = __builtin_amdgcn_mfma_f32_16x16x32_f16(
                    af[mt], bf[nt], acc[mt][nt], 0, 0, 0);
    }
    float* outz = fpart + (size_t)blockIdx.z * NIMG * FF;
#pragma unroll
    for (int mt = 0; mt < 2; mt++)
#pragma unroll
        for (int nt = 0; nt < 4; nt++)
#pragma unroll
            for (int i = 0; i < 4; i++) {
                const int gm = m0 + wm + mt * 16 + quad * 4 + i;
                const int gn = n0 + wn + nt * 16 + l16;
                outz[(size_t)gm * FF + gn] = acc[mt][nt][i];
            }
}

// ---------------- K2b: sum 16 split-K partials + bias + relu ----------------
__global__ __launch_bounds__(256)
void bias_sum_relu(const float* __restrict__ fpart, const float* __restrict__ bias,
                   float* __restrict__ f) {
    const size_t idx = ((size_t)blockIdx.x * 256 + threadIdx.x) * 4;
    float4 s = make_float4(0.f, 0.f, 0.f, 0.f);
#pragma unroll
    for (int z = 0; z < KSPLIT; z++) {
        float4 v = *(const float4*)(fpart + (size_t)z * NIMG * FF + idx);
        s.x += v.x; s.y += v.y; s.z += v.z; s.w += v.w;
    }
    const int col = (int)(idx & (FF - 1));
    float4 bv = *(const float4*)(bias + col);
    float4 o;
    o.x = fmaxf(s.x + bv.x, 0.f);
    o.y = fmaxf(s.y + bv.y, 0.f);
    o.z = fmaxf(s.z + bv.z, 0.f);
    o.w = fmaxf(s.w + bv.w, 0.f);
    *(float4*)(f + idx) = o;
}

// ---------------- K3a: row squared norms ----------------
__global__ __launch_bounds__(512)
void rownorm(const float* __restrict__ feats, float* __restrict__ n2) {
    const int b = blockIdx.x;
    const int tid = threadIdx.x, hw = tid >> 5, l = tid & 31;
#pragma unroll
    for (int r = 0; r < 6; r++) {
        const int row = hw * 6 + r;
        const float* fr = feats + ((size_t)b * SS + row) * FF;
        float s = 0.f;
#pragma unroll
        for (int u = 0; u < 8; u++) { float v = fr[l + 32 * u]; s += v * v; }
#pragma unroll
        for (int mm = 16; mm >= 1; mm >>= 1) s += __shfl_xor(s, mm);
        if (l == 0) n2[b * SS + row] = s;
    }
}

// ---------------- K3b: D = clamp(n2_i + n2_j - 2<f_i,f_j>, 0) ----------------
__global__ __launch_bounds__(256)
void dmat(const float* __restrict__ feats, const float* __restrict__ n2,
          float* __restrict__ Dm) {
    const int i0 = blockIdx.x * 16, j0 = blockIdx.y * 16, b = blockIdx.z;
    __shared__ float fi[16][260], fj[16][260];
    const int tid = threadIdx.x;
    const int r = tid >> 4, c0 = (tid & 15) * 16;
    const float* fbase = feats + (size_t)b * SS * FF;
#pragma unroll
    for (int v = 0; v < 16; v += 4) {
        float4 a = *(const float4*)(fbase + (size_t)(i0 + r) * FF + c0 + v);
        float4 w = *(const float4*)(fbase + (size_t)(j0 + r) * FF + c0 + v);
        *(float4*)&fi[r][c0 + v] = a;
        *(float4*)&fj[r][c0 + v] = w;
    }
    __syncthreads();
    const int ti = tid >> 4, tj = tid & 15;
    float dot = 0.f;
#pragma unroll 4
    for (int f = 0; f < FF; f += 4) {
        float4 a = *(const float4*)&fi[ti][f];
        float4 w = *(const float4*)&fj[tj][f];
        dot += a.x * w.x + a.y * w.y + a.z * w.z + a.w * w.w;
    }
    const int i = i0 + ti, j = j0 + tj;
    const float d = n2[b * SS + i] + n2[b * SS + j] - 2.f * dot;
    Dm[((size_t)b * SS + i) * SS + j] = fmaxf(d, 0.f);
}

// ---------------- K4: robust-OT solve, v3 (known-good 306us version) ----------------
__global__ __launch_bounds__(512)
void ot_kernel(const float* __restrict__ Dg, const float* __restrict__ Qg,
               const float* __restrict__ thetag, float* __restrict__ ppub,
               unsigned* __restrict__ bar, float* __restrict__ out) {
    const int bk = blockIdx.x;
    const int b = bk / KK, k = bk % KK;
    const int tid = threadIdx.x;
    const int hw = tid >> 5, l = tid & 31;

    __shared__ float ppart[16][SS];
    __shared__ float cpart[16];
    __shared__ float Msh[SS];
    __shared__ float pown[SS];
    __shared__ float costsh, lamsh;

    float a[6][3], e[6][3], dre[6][3], rz[6], qi[6];

    const float* Db = Dg + (size_t)b * SS * SS;
    const float* Qb = Qg + ((size_t)b * KK + k) * SS;
#pragma unroll
    for (int r = 0; r < 6; r++) {
        const int i = hw * 6 + r;
#pragma unroll
        for (int u = 0; u < 3; u++) dre[r][u] = Db[i * SS + l + 32 * u];
        qi[r] = Qb[i];
    }
    const float th = thetag[k];
    unsigned* ctr = bar + b * 64;
    unsigned target = 0;

    auto publish_and_wait = [&](int buf) {
        if (tid < SS)
            __hip_atomic_store(&ppub[(((size_t)buf * BB + b) * KK + k) * SS + tid],
                               pown[tid], __ATOMIC_RELAXED, __HIP_MEMORY_SCOPE_AGENT);
        asm volatile("s_waitcnt vmcnt(0)" ::: "memory");
        __syncthreads();
        target += KK;
        if (tid == 0) {
            __hip_atomic_fetch_add(ctr, 1u, __ATOMIC_RELAXED, __HIP_MEMORY_SCOPE_AGENT);
            while (__hip_atomic_load(ctr, __ATOMIC_RELAXED, __HIP_MEMORY_SCOPE_AGENT) < target)
                __builtin_amdgcn_s_sleep(2);
        }
        __syncthreads();
    };

    auto collect = [&]() {
        __syncthreads();
        if (tid < SS) {
            float s = 0.f;
#pragma unroll
            for (int h = 0; h < 16; h++) s += ppart[h][tid];
            pown[tid] = s;
        }
        if (tid == 0) {
            float c = 0.f;
#pragma unroll
            for (int h = 0; h < 16; h++) c += cpart[h];
            costsh = c;
            lamsh = 2.f * RHOC * fmaxf(c - th, 0.f);
        }
        __syncthreads();
    };

    {
        float cd[6];
#pragma unroll
        for (int r = 0; r < 6; r++) {
#pragma unroll
            for (int u = 0; u < 3; u++) { a[r][u] = 0.f; e[r][u] = 1.f; }
            rz[r] = 1.f / 96.f;
            cd[r] = dre[r][0] + dre[r][1] + dre[r][2];
        }
#pragma unroll
        for (int mm = 16; mm >= 1; mm >>= 1)
#pragma unroll
            for (int r = 0; r < 6; r++) cd[r] += __shfl_xor(cd[r], mm);
        float pp0 = 0.f, cc = 0.f;
#pragma unroll
        for (int r = 0; r < 6; r++) {
            const float scale = qi[r] * rz[r];
            pp0 += scale;
            cc += scale * cd[r];
        }
        ppart[hw][l] = pp0; ppart[hw][l + 32] = pp0; ppart[hw][l + 64] = pp0;
        if (l == 0) cpart[hw] = cc;
        collect();
    }
    publish_and_wait(0);

    for (int t = 0; t < NSTEPS; t++) {
        const int rbuf = t & 1;
        if (tid < SS) {
            const float* ps = ppub + (((size_t)rbuf * BB + b) * KK) * SS + tid;
            float v[KK];
            float mx = -1e30f;
#pragma unroll
            for (int kk2 = 0; kk2 < KK; kk2++) {
                v[kk2] = __hip_atomic_load(&ps[kk2 * SS], __ATOMIC_RELAXED,
                                           __HIP_MEMORY_SCOPE_AGENT) * TAUI;
                mx = fmaxf(mx, v[kk2]);
            }
            float sum = 0.f;
#pragma unroll
            for (int kk2 = 0; kk2 < KK; kk2++) sum += __expf(v[kk2] - mx);
            Msh[tid] = __expf(v[k] - mx) * __builtin_amdgcn_rcpf(sum);
        }
        __syncthreads();
        const float lam = lamsh;
        const float M0 = Msh[l], M1 = Msh[l + 32], M2 = Msh[l + 64];

        float g[6][3], dt[6];
#pragma unroll
        for (int r = 0; r < 6; r++) {
            g[r][0] = fmaf(lam, dre[r][0], M0);
            g[r][1] = fmaf(lam, dre[r][1], M1);
            g[r][2] = fmaf(lam, dre[r][2], M2);
            dt[r] = (e[r][0] * g[r][0] + e[r][1] * g[r][1] + e[r][2] * g[r][2]) * rz[r];
        }
#pragma unroll
        for (int mm = 16; mm >= 1; mm >>= 1)
#pragma unroll
            for (int r = 0; r < 6; r++) dt[r] += __shfl_xor(dt[r], mm);

        float mrow[6];
#pragma unroll
        for (int r = 0; r < 6; r++) {
            const float cq = LRC * qi[r] * rz[r];
            a[r][0] -= cq * e[r][0] * (g[r][0] - dt[r]);
            a[r][1] -= cq * e[r][1] * (g[r][1] - dt[r]);
            a[r][2] -= cq * e[r][2] * (g[r][2] - dt[r]);
            mrow[r] = fmaxf(a[r][0], fmaxf(a[r][1], a[r][2]));
        }
#pragma unroll
        for (int mm = 16; mm >= 1; mm >>= 1)
#pragma unroll
            for (int r = 0; r < 6; r++) mrow[r] = fmaxf(mrow[r], __shfl_xor(mrow[r], mm));

        float zz[6], cd[6];
#pragma unroll
        for (int r = 0; r < 6; r++) {
            e[r][0] = __expf(a[r][0] - mrow[r]);
            e[r][1] = __expf(a[r][1] - mrow[r]);
            e[r][2] = __expf(a[r][2] - mrow[r]);
            zz[r] = e[r][0] + e[r][1] + e[r][2];
            cd[r] = e[r][0] * dre[r][0] + e[r][1] * dre[r][1] + e[r][2] * dre[r][2];
        }
#pragma unroll
        for (int mm = 16; mm >= 1; mm >>= 1)
#pragma unroll
            for (int r = 0; r < 6; r++) {
                zz[r] += __shfl_xor(zz[r], mm);
                cd[r] += __shfl_xor(cd[r], mm);
            }

        float pp0 = 0.f, pp1 = 0.f, pp2 = 0.f, cc = 0.f;
#pragma unroll
        for (int r = 0; r < 6; r++) {
            const float rzz = __builtin_amdgcn_rcpf(zz[r]);
            rz[r] = rzz;
            const float scale = qi[r] * rzz;
            pp0 += scale * e[r][0];
            pp1 += scale * e[r][1];
            pp2 += scale * e[r][2];
            cc += scale * cd[r];
        }
        ppart[hw][l] = pp0; ppart[hw][l + 32] = pp1; ppart[hw][l + 64] = pp2;
        if (l == 0) cpart[hw] = cc;
        collect();
        if (t < NSTEPS - 1) publish_and_wait((t + 1) & 1);
    }
    if (tid < SS) out[((size_t)b * KK + k) * SS + tid] = pown[tid];
}

// ---------------- launch ----------------
extern "C" void kernel_launch(void* const* d_in, const int* in_sizes, int n_in,
                              void* d_out, int out_size, void* d_ws, size_t ws_size,
                              hipStream_t stream) {
    const float* X     = (const float*)d_in[0];
    const float* Q     = (const float*)d_in[1];
    const float* convw = (const float*)d_in[2];
    const float* convb = (const float*)d_in[3];
    const float* fcw   = (const float*)d_in[4];
    const float* fcb   = (const float*)d_in[5];
    const float* theta = (const float*)d_in[6];
    float* out = (float*)d_out;

    char* ws = (char*)d_ws;
    size_t off = 0;
    auto take = [&](size_t nbytes) {
        char* p = ws + off;
        off += (nbytes + 255) & ~(size_t)255;
        return (void*)p;
    };
    _Float16* pooled = (_Float16*)take((size_t)NIMG * FDIM * 2);       // 94.5 MB
    _Float16* Wh     = (_Float16*)take((size_t)FF * FDIM * 2);         // 15.7 MB
    float*    fpart  = (float*)take((size_t)KSPLIT * NIMG * FF * 4);   // 25.2 MB
    float*    feats  = (float*)take((size_t)NIMG * FF * 4);
    float*    n2     = (float*)take((size_t)NIMG * 4);
    float*    Dm     = (float*)take((size_t)BB * SS * SS * 4);
    float*    ppub   = (float*)take((size_t)2 * BB * KK * SS * 4);
    __fp16*   wpp    = (__fp16*)take((size_t)288 * 8 * 2);             // paired conv weights
    unsigned* bar    = (unsigned*)take((size_t)BB * 64 * 4);

    (void)hipMemsetAsync(bar, 0, (size_t)BB * 64 * 4, stream);

    hipLaunchKernelGGL(wcast, dim3((FF * FDIM) / 1024), dim3(256), 0, stream, fcw, Wh);
    hipLaunchKernelGGL(wprep, dim3(5), dim3(64), 0, stream, convw, wpp);
    hipLaunchKernelGGL(conv_pool, dim3(4, NIMG), dim3(256), 0, stream,
                       X, (const uint4*)wpp, convb, pooled);
    hipLaunchKernelGGL(fc_gemm, dim3(24, 2, KSPLIT), dim3(256), 0, stream, pooled, Wh, fpart);
    hipLaunchKernelGGL(bias_sum_relu, dim3(NIMG * FF / 1024), dim3(256), 0, stream, fpart, fcb, feats);
    hipLaunchKernelGGL(rownorm, dim3(BB), dim3(512), 0, stream, feats, n2);
    hipLaunchKernelGGL(dmat, dim3(6, 6, BB), dim3(256), 0, stream, feats, n2, Dm);
    hipLaunchKernelGGL(ot_kernel, dim3(BB * KK), dim3(512), 0, stream, Dm, Q, theta, ppub, bar, out);
}

// Round 9
// 607.436 us; speedup vs baseline: 1.1606x; 1.0043x over previous
//
#include <hip/hip_runtime.h>

// Problem dims
#define BB 16
#define SS 96
#define KK 10
#define FF 256
#define IH 64
#define IW 64
#define OCH 32
#define PH 31
#define PW 31
#define NPOS 961          // 31*31
#define FDIM 30752        // 32*961
#define NIMG 1536         // 16*96

// Solver hyper-params
#define TAUI 20.0f        // 1/TAU
#define RHOC 10.0f
#define LRC  0.5f
#define NSTEPS 60

// fc_gemm split-K: 30752 = 31 * 992, 992 = 31 k-steps of 32
#define KSPLIT 31
#define KCHE 992

typedef _Float16 v8hf __attribute__((ext_vector_type(8)));
typedef _Float16 v4hf __attribute__((ext_vector_type(4)));
typedef __fp16 h2 __attribute__((ext_vector_type(2)));
typedef float v4f __attribute__((ext_vector_type(4)));

// ---------------- K0a: fc weight fp32 -> fp16 ----------------
__global__ __launch_bounds__(256)
void wcast(const float* __restrict__ w, _Float16* __restrict__ wh) {
    const size_t i = ((size_t)blockIdx.x * 256 + threadIdx.x) * 4;
    float4 v = *(const float4*)(w + i);
    v4hf o = {(_Float16)v.x, (_Float16)v.y, (_Float16)v.z, (_Float16)v.w};
    *(v4hf*)(wh + i) = o;
}

// ---------------- K0b: conv weight -> paired fp16 quads ----------------
__global__ __launch_bounds__(64)
void wprep(const float* __restrict__ w, __fp16* __restrict__ wp) {
    const int t = blockIdx.x * 64 + threadIdx.x;   // 288 triples
    if (t >= 288) return;
    const float* s = w + t * 3;
    const __fp16 w0 = (__fp16)s[0], w1 = (__fp16)s[1], w2 = (__fp16)s[2];
    __fp16* d = wp + t * 8;
    d[0] = w0; d[1] = w1;
    d[2] = w2; d[3] = (__fp16)0.f;
    d[4] = (__fp16)0.f; d[5] = w0;
    d[6] = w1; d[7] = w2;
}

// ---------------- K1: conv3x3 + bias + relu + maxpool2x2 -> fp16, via v_dot2_f32_f16 ----------------
__global__ __launch_bounds__(256)
void conv_pool(const float* __restrict__ X, const uint4* __restrict__ wp,
               const float* __restrict__ bias, _Float16* __restrict__ pooled) {
    __shared__ uint4 wsl[288];
    const int tid = threadIdx.x;
    for (int i = tid; i < 288; i += 256) wsl[i] = wp[i];
    __syncthreads();

    const int img = blockIdx.y;
    const int pos = blockIdx.x * 256 + tid;
    if (pos >= NPOS) return;
    const int oy = pos / PW, ox = pos % PW;
    const int iy = 2 * oy, ix = 2 * ox;
    const float* xb = X + (size_t)img * 3 * IH * IW;
    h2 inh[3][4][2];
#pragma unroll
    for (int c = 0; c < 3; c++)
#pragma unroll
        for (int r = 0; r < 4; r++) {
            const float* row = xb + ((size_t)c * IH + iy + r) * IW + ix;
            float2 p0 = *(const float2*)(row);
            float2 p1 = *(const float2*)(row + 2);
            inh[c][r][0] = __builtin_amdgcn_cvt_pkrtz(p0.x, p0.y);
            inh[c][r][1] = __builtin_amdgcn_cvt_pkrtz(p1.x, p1.y);
        }
    _Float16* outp = pooled + (size_t)img * FDIM + pos;
    for (int oc = 0; oc < OCH; oc++) {
        float a00 = 0.f, a01 = 0.f, a10 = 0.f, a11 = 0.f;
#pragma unroll
        for (int c = 0; c < 3; c++)
#pragma unroll
            for (int ky = 0; ky < 3; ky++) {
                const h2* q = (const h2*)(wsl + oc * 9 + c * 3 + ky);
                a00 = __builtin_amdgcn_fdot2(inh[c][ky][0], q[0], a00, false);
                a00 = __builtin_amdgcn_fdot2(inh[c][ky][1], q[1], a00, false);
                a01 = __builtin_amdgcn_fdot2(inh[c][ky][0], q[2], a01, false);
                a01 = __builtin_amdgcn_fdot2(inh[c][ky][1], q[3], a01, false);
                a10 = __builtin_amdgcn_fdot2(inh[c][ky + 1][0], q[0], a10, false);
                a10 = __builtin_amdgcn_fdot2(inh[c][ky + 1][1], q[1], a10, false);
                a11 = __builtin_amdgcn_fdot2(inh[c][ky + 1][0], q[2], a11, false);
                a11 = __builtin_amdgcn_fdot2(inh[c][ky + 1][1], q[3], a11, false);
            }
        float m = fmaxf(fmaxf(a00, a01), fmaxf(a10, a11)) + bias[oc];
        outp[(size_t)oc * NPOS] = (_Float16)fmaxf(m, 0.f);
    }
}

// ---------------- K2: FC GEMM fp16 MFMA, 128x128 tile, split-K=31, plain-store partials ----------------
// CORRECTED staging (R8 bug: only half the 32-half K-slice was written):
// each thread loads 2 uint4 per matrix: 256 thr x 2 x 8 halves = 4096 = 128x32.
__global__ __launch_bounds__(256)
void fc_gemm(const _Float16* __restrict__ Ah, const _Float16* __restrict__ Wh,
             float* __restrict__ fpart) {
    __shared__ _Float16 Asl[128 * 56];
    __shared__ _Float16 Bsl[128 * 56];
    const int m0 = blockIdx.x * 128, n0 = blockIdx.y * 128;
    const int k0 = blockIdx.z * KCHE;
    const int tid = threadIdx.x;
    const int wave = tid >> 6, lane = tid & 63;
    const int quad = lane >> 4, l16 = lane & 15;
    const int wm = (wave & 1) * 64, wn = (wave >> 1) * 64;
    const int ar = tid >> 1, ac = (tid & 1) * 16;   // row 0..127, halves [ac,ac+16)
    const _Float16* Ag = Ah + (size_t)(m0 + ar) * FDIM + ac;
    const _Float16* Bg = Wh + (size_t)(n0 + ar) * FDIM + ac;

    v4f acc[4][4];
#pragma unroll
    for (int i = 0; i < 4; i++)
#pragma unroll
        for (int j = 0; j < 4; j++) acc[i][j] = (v4f)(0.f);

    for (int s = 0; s < KCHE / 32; s++) {
        const int gk = k0 + (s << 5);
        uint4 a0 = *(const uint4*)(Ag + gk);
        uint4 a1 = *(const uint4*)(Ag + gk + 8);
        uint4 b0 = *(const uint4*)(Bg + gk);
        uint4 b1 = *(const uint4*)(Bg + gk + 8);
        __syncthreads();
        *(uint4*)&Asl[ar * 56 + ac] = a0;
        *(uint4*)&Asl[ar * 56 + ac + 8] = a1;
        *(uint4*)&Bsl[ar * 56 + ac] = b0;
        *(uint4*)&Bsl[ar * 56 + ac + 8] = b1;
        __syncthreads();
        v8hf af[4], bf[4];
#pragma unroll
        for (int mt = 0; mt < 4; mt++)
            af[mt] = *(const v8hf*)&Asl[(wm + mt * 16 + l16) * 56 + quad * 8];
#pragma unroll
        for (int nt = 0; nt < 4; nt++)
            bf[nt] = *(const v8hf*)&Bsl[(wn + nt * 16 + l16) * 56 + quad * 8];
#pragma unroll
        for (int mt = 0; mt < 4; mt++)
#pragma unroll
            for (int nt = 0; nt < 4; nt++)
                acc[mt][nt] = __builtin_amdgcn_mfma_f32_16x16x32_f16(
                    af[mt], bf[nt], acc[mt][nt], 0, 0, 0);
    }
    float* outz = fpart + (size_t)blockIdx.z * NIMG * FF;
#pragma unroll
    for (int mt = 0; mt < 4; mt++)
#pragma unroll
        for (int nt = 0; nt < 4; nt++)
#pragma unroll
            for (int i = 0; i < 4; i++) {
                const int gm = m0 + wm + mt * 16 + quad * 4 + i;
                const int gn = n0 + wn + nt * 16 + l16;
                outz[(size_t)gm * FF + gn] = acc[mt][nt][i];
            }
}

// ---------------- K2b: sum 31 split-K partials + bias + relu ----------------
__global__ __launch_bounds__(256)
void bias_sum_relu(const float* __restrict__ fpart, const float* __restrict__ bias,
                   float* __restrict__ f) {
    const size_t idx = ((size_t)blockIdx.x * 256 + threadIdx.x) * 4;
    float4 s = make_float4(0.f, 0.f, 0.f, 0.f);
#pragma unroll
    for (int z = 0; z < KSPLIT; z++) {
        float4 v = *(const float4*)(fpart + (size_t)z * NIMG * FF + idx);
        s.x += v.x; s.y += v.y; s.z += v.z; s.w += v.w;
    }
    const int col = (int)(idx & (FF - 1));
    float4 bv = *(const float4*)(bias + col);
    float4 o;
    o.x = fmaxf(s.x + bv.x, 0.f);
    o.y = fmaxf(s.y + bv.y, 0.f);
    o.z = fmaxf(s.z + bv.z, 0.f);
    o.w = fmaxf(s.w + bv.w, 0.f);
    *(float4*)(f + idx) = o;
}

// ---------------- K3a: row squared norms ----------------
__global__ __launch_bounds__(512)
void rownorm(const float* __restrict__ feats, float* __restrict__ n2) {
    const int b = blockIdx.x;
    const int tid = threadIdx.x, hw = tid >> 5, l = tid & 31;
#pragma unroll
    for (int r = 0; r < 6; r++) {
        const int row = hw * 6 + r;
        const float* fr = feats + ((size_t)b * SS + row) * FF;
        float s = 0.f;
#pragma unroll
        for (int u = 0; u < 8; u++) { float v = fr[l + 32 * u]; s += v * v; }
#pragma unroll
        for (int mm = 16; mm >= 1; mm >>= 1) s += __shfl_xor(s, mm);
        if (l == 0) n2[b * SS + row] = s;
    }
}

// ---------------- K3b: D = clamp(n2_i + n2_j - 2<f_i,f_j>, 0) ----------------
__global__ __launch_bounds__(256)
void dmat(const float* __restrict__ feats, const float* __restrict__ n2,
          float* __restrict__ Dm) {
    const int i0 = blockIdx.x * 16, j0 = blockIdx.y * 16, b = blockIdx.z;
    __shared__ float fi[16][260], fj[16][260];
    const int tid = threadIdx.x;
    const int r = tid >> 4, c0 = (tid & 15) * 16;
    const float* fbase = feats + (size_t)b * SS * FF;
#pragma unroll
    for (int v = 0; v < 16; v += 4) {
        float4 a = *(const float4*)(fbase + (size_t)(i0 + r) * FF + c0 + v);
        float4 w = *(const float4*)(fbase + (size_t)(j0 + r) * FF + c0 + v);
        *(float4*)&fi[r][c0 + v] = a;
        *(float4*)&fj[r][c0 + v] = w;
    }
    __syncthreads();
    const int ti = tid >> 4, tj = tid & 15;
    float dot = 0.f;
#pragma unroll 4
    for (int f = 0; f < FF; f += 4) {
        float4 a = *(const float4*)&fi[ti][f];
        float4 w = *(const float4*)&fj[tj][f];
        dot += a.x * w.x + a.y * w.y + a.z * w.z + a.w * w.w;
    }
    const int i = i0 + ti, j = j0 + tj;
    const float d = n2[b * SS + i] + n2[b * SS + j] - 2.f * dot;
    Dm[((size_t)b * SS + i) * SS + j] = fmaxf(d, 0.f);
}

// ---------------- K4: robust-OT solve, v3 (proven 306us version, byte-for-byte) ----------------
__global__ __launch_bounds__(512)
void ot_kernel(const float* __restrict__ Dg, const float* __restrict__ Qg,
               const float* __restrict__ thetag, float* __restrict__ ppub,
               unsigned* __restrict__ bar, float* __restrict__ out) {
    const int bk = blockIdx.x;
    const int b = bk / KK, k = bk % KK;
    const int tid = threadIdx.x;
    const int hw = tid >> 5, l = tid & 31;

    __shared__ float ppart[16][SS];
    __shared__ float cpart[16];
    __shared__ float Msh[SS];
    __shared__ float pown[SS];
    __shared__ float costsh, lamsh;

    float a[6][3], e[6][3], dre[6][3], rz[6], qi[6];

    const float* Db = Dg + (size_t)b * SS * SS;
    const float* Qb = Qg + ((size_t)b * KK + k) * SS;
#pragma unroll
    for (int r = 0; r < 6; r++) {
        const int i = hw * 6 + r;
#pragma unroll
        for (int u = 0; u < 3; u++) dre[r][u] = Db[i * SS + l + 32 * u];
        qi[r] = Qb[i];
    }
    const float th = thetag[k];
    unsigned* ctr = bar + b * 64;
    unsigned target = 0;

    auto publish_and_wait = [&](int buf) {
        if (tid < SS)
            __hip_atomic_store(&ppub[(((size_t)buf * BB + b) * KK + k) * SS + tid],
                               pown[tid], __ATOMIC_RELAXED, __HIP_MEMORY_SCOPE_AGENT);
        asm volatile("s_waitcnt vmcnt(0)" ::: "memory");
        __syncthreads();
        target += KK;
        if (tid == 0) {
            __hip_atomic_fetch_add(ctr, 1u, __ATOMIC_RELAXED, __HIP_MEMORY_SCOPE_AGENT);
            while (__hip_atomic_load(ctr, __ATOMIC_RELAXED, __HIP_MEMORY_SCOPE_AGENT) < target)
                __builtin_amdgcn_s_sleep(2);
        }
        __syncthreads();
    };

    auto collect = [&]() {
        __syncthreads();
        if (tid < SS) {
            float s = 0.f;
#pragma unroll
            for (int h = 0; h < 16; h++) s += ppart[h][tid];
            pown[tid] = s;
        }
        if (tid == 0) {
            float c = 0.f;
#pragma unroll
            for (int h = 0; h < 16; h++) c += cpart[h];
            costsh = c;
            lamsh = 2.f * RHOC * fmaxf(c - th, 0.f);
        }
        __syncthreads();
    };

    {
        float cd[6];
#pragma unroll
        for (int r = 0; r < 6; r++) {
#pragma unroll
            for (int u = 0; u < 3; u++) { a[r][u] = 0.f; e[r][u] = 1.f; }
            rz[r] = 1.f / 96.f;
            cd[r] = dre[r][0] + dre[r][1] + dre[r][2];
        }
#pragma unroll
        for (int mm = 16; mm >= 1; mm >>= 1)
#pragma unroll
            for (int r = 0; r < 6; r++) cd[r] += __shfl_xor(cd[r], mm);
        float pp0 = 0.f, cc = 0.f;
#pragma unroll
        for (int r = 0; r < 6; r++) {
            const float scale = qi[r] * rz[r];
            pp0 += scale;
            cc += scale * cd[r];
        }
        ppart[hw][l] = pp0; ppart[hw][l + 32] = pp0; ppart[hw][l + 64] = pp0;
        if (l == 0) cpart[hw] = cc;
        collect();
    }
    publish_and_wait(0);

    for (int t = 0; t < NSTEPS; t++) {
        const int rbuf = t & 1;
        if (tid < SS) {
            const float* ps = ppub + (((size_t)rbuf * BB + b) * KK) * SS + tid;
            float v[KK];
            float mx = -1e30f;
#pragma unroll
            for (int kk2 = 0; kk2 < KK; kk2++) {
                v[kk2] = __hip_atomic_load(&ps[kk2 * SS], __ATOMIC_RELAXED,
                                           __HIP_MEMORY_SCOPE_AGENT) * TAUI;
                mx = fmaxf(mx, v[kk2]);
            }
            float sum = 0.f;
#pragma unroll
            for (int kk2 = 0; kk2 < KK; kk2++) sum += __expf(v[kk2] - mx);
            Msh[tid] = __expf(v[k] - mx) * __builtin_amdgcn_rcpf(sum);
        }
        __syncthreads();
        const float lam = lamsh;
        const float M0 = Msh[l], M1 = Msh[l + 32], M2 = Msh[l + 64];

        float g[6][3], dt[6];
#pragma unroll
        for (int r = 0; r < 6; r++) {
            g[r][0] = fmaf(lam, dre[r][0], M0);
            g[r][1] = fmaf(lam, dre[r][1], M1);
            g[r][2] = fmaf(lam, dre[r][2], M2);
            dt[r] = (e[r][0] * g[r][0] + e[r][1] * g[r][1] + e[r][2] * g[r][2]) * rz[r];
        }
#pragma unroll
        for (int mm = 16; mm >= 1; mm >>= 1)
#pragma unroll
            for (int r = 0; r < 6; r++) dt[r] += __shfl_xor(dt[r], mm);

        float mrow[6];
#pragma unroll
        for (int r = 0; r < 6; r++) {
            const float cq = LRC * qi[r] * rz[r];
            a[r][0] -= cq * e[r][0] * (g[r][0] - dt[r]);
            a[r][1] -= cq * e[r][1] * (g[r][1] - dt[r]);
            a[r][2] -= cq * e[r][2] * (g[r][2] - dt[r]);
            mrow[r] = fmaxf(a[r][0], fmaxf(a[r][1], a[r][2]));
        }
#pragma unroll
        for (int mm = 16; mm >= 1; mm >>= 1)
#pragma unroll
            for (int r = 0; r < 6; r++) mrow[r] = fmaxf(mrow[r], __shfl_xor(mrow[r], mm));

        float zz[6], cd[6];
#pragma unroll
        for (int r = 0; r < 6; r++) {
            e[r][0] = __expf(a[r][0] - mrow[r]);
            e[r][1] = __expf(a[r][1] - mrow[r]);
            e[r][2] = __expf(a[r][2] - mrow[r]);
            zz[r] = e[r][0] + e[r][1] + e[r][2];
            cd[r] = e[r][0] * dre[r][0] + e[r][1] * dre[r][1] + e[r][2] * dre[r][2];
        }
#pragma unroll
        for (int mm = 16; mm >= 1; mm >>= 1)
#pragma unroll
            for (int r = 0; r < 6; r++) {
                zz[r] += __shfl_xor(zz[r], mm);
                cd[r] += __shfl_xor(cd[r], mm);
            }

        float pp0 = 0.f, pp1 = 0.f, pp2 = 0.f, cc = 0.f;
#pragma unroll
        for (int r = 0; r < 6; r++) {
            const float rzz = __builtin_amdgcn_rcpf(zz[r]);
            rz[r] = rzz;
            const float scale = qi[r] * rzz;
            pp0 += scale * e[r][0];
            pp1 += scale * e[r][1];
            pp2 += scale * e[r][2];
            cc += scale * cd[r];
        }
        ppart[hw][l] = pp0; ppart[hw][l + 32] = pp1; ppart[hw][l + 64] = pp2;
        if (l == 0) cpart[hw] = cc;
        collect();
        if (t < NSTEPS - 1) publish_and_wait((t + 1) & 1);
    }
    if (tid < SS) out[((size_t)b * KK + k) * SS + tid] = pown[tid];
}

// ---------------- launch ----------------
extern "C" void kernel_launch(void* const* d_in, const int* in_sizes, int n_in,
                              void* d_out, int out_size, void* d_ws, size_t ws_size,
                              hipStream_t stream) {
    const float* X     = (const float*)d_in[0];
    const float* Q     = (const float*)d_in[1];
    const float* convw = (const float*)d_in[2];
    const float* convb = (const float*)d_in[3];
    const float* fcw   = (const float*)d_in[4];
    const float* fcb   = (const float*)d_in[5];
    const float* theta = (const float*)d_in[6];
    float* out = (float*)d_out;

    char* ws = (char*)d_ws;
    size_t off = 0;
    auto take = [&](size_t nbytes) {
        char* p = ws + off;
        off += (nbytes + 255) & ~(size_t)255;
        return (void*)p;
    };
    _Float16* pooled = (_Float16*)take((size_t)NIMG * FDIM * 2);       // 94.5 MB
    _Float16* Wh     = (_Float16*)take((size_t)FF * FDIM * 2);         // 15.7 MB
    float*    fpart  = (float*)take((size_t)KSPLIT * NIMG * FF * 4);   // 48.8 MB
    float*    feats  = (float*)take((size_t)NIMG * FF * 4);
    float*    n2     = (float*)take((size_t)NIMG * 4);
    float*    Dm     = (float*)take((size_t)BB * SS * SS * 4);
    float*    ppub   = (float*)take((size_t)2 * BB * KK * SS * 4);
    __fp16*   wpp    = (__fp16*)take((size_t)288 * 8 * 2);
    unsigned* bar    = (unsigned*)take((size_t)BB * 64 * 4);

    (void)hipMemsetAsync(bar, 0, (size_t)BB * 64 * 4, stream);

    hipLaunchKernelGGL(wcast, dim3((FF * FDIM) / 1024), dim3(256), 0, stream, fcw, Wh);
    hipLaunchKernelGGL(wprep, dim3(5), dim3(64), 0, stream, convw, wpp);
    hipLaunchKernelGGL(conv_pool, dim3(4, NIMG), dim3(256), 0, stream,
                       X, (const uint4*)wpp, convb, pooled);
    hipLaunchKernelGGL(fc_gemm, dim3(12, 2, KSPLIT), dim3(256), 0, stream, pooled, Wh, fpart);
    hipLaunchKernelGGL(bias_sum_relu, dim3(NIMG * FF / 1024), dim3(256), 0, stream, fpart, fcb, feats);
    hipLaunchKernelGGL(rownorm, dim3(BB), dim3(512), 0, stream, feats, n2);
    hipLaunchKernelGGL(dmat, dim3(6, 6, BB), dim3(256), 0, stream, feats, n2, Dm);
    hipLaunchKernelGGL(ot_kernel, dim3(BB * KK), dim3(512), 0, stream, Dm, Q, theta, ppub, bar, out);
}